// Round 5
// baseline (197.341 us; speedup 1.0000x reference)
//
#include <hip/hip_runtime.h>

// ShapeAwareRoIAlign: mask-weighted RoIAlign.
//   features: [N=2, C=256, H=200, W=200] f32 (NCHW, 164 MB)
//   rois:     [R=512, 5] f32  (b, x1, y1, x2, y2) inclusive image coords
//   masks:    [R, MH=128, MW=128] f32
//   out:      [R, C, 7, 7] f32
//
// Round 11. Harness model (validated by residual accounting r0-r4): the two
// ~49 us fillBuffer restores (~110 us with launch overhead) are UNCONDITIONAL
// -- they run whether or not d_ws is touched. Total = ~110 + kernels; kernel
// byte floor ~30 us (168 MB fetch + 25.7 MB write at 6.6 TB/s).
// Round-10 kernel was 68.7 us, VALUBusy 60%: staging cost ~55 VALU per 32 B
// (f2bf x8 + pack + ds_write) on a serial load->convert->write chain.
// This round: stage the region as F32 via __builtin_amdgcn_global_load_lds
// (width 16, HBM->LDS direct, no VGPR round-trip, no conversion, no
// waitcnt until the barrier). Mask loads issue BEFORE the staging burst so
// all latencies overlap. Gather = ds_read_b32 + fmaf (no unpack). Grid is
// cg-fastest so a roi's 32 blocks co-run: masks + region fetched once,
// L2-served for the rest.

constexpr int   OUT_H = 7, OUT_W = 7;
constexpr int   NBIN  = OUT_H * OUT_W;     // 49
constexpr float SCALE = 0.25f;
constexpr int   S     = 2;
constexpr int   NSAMP = NBIN * S * S;      // 196 sample points per roi
constexpr int   CG    = 8;                 // channels per block
constexpr int   RDIM  = 34;                // max region rows
constexpr int   RCOLS4 = 10;               // max float4 cols
constexpr int   MAXIT  = RDIM * RCOLS4;    // 340 float4 items per channel
constexpr int   CH_DW  = MAXIT * 4 + 4;    // 1364 dwords per channel:
                                           // 16B-aligned; 1364%32=20 -> the 8
                                           // channel bases hit 8 distinct banks

typedef unsigned short ushort_t;

// ---------------------------------------------------------------------------
// Fused direct kernel: grid (C/8, R), 256 threads, no workspace.
//   A: threads 0..195 compute sample coords and ISSUE 4 mask loads.
//   B: all threads issue global_load_lds x (<=12 per wave): region [8ch]
//      packed [item]=[ry][4k] f32, fire-and-forget (vmcnt drained at barrier).
//   C: threads 0..195 finish geometry: region-local BYTE offsets + folded
//      weights (bilinear*mask*valid*0.25) -> s_idx/s_w.
//   D: gather: thread=(c 0..7, sg 0..31); bins sg, sg+32; ds_read_b32+fmaf.
//   E: results via LDS (reuse region buffer), coalesced out.
// ---------------------------------------------------------------------------
__global__ __launch_bounds__(256, 3)
void roialign_direct_kernel(const float* __restrict__ features,
                            const float* __restrict__ rois,
                            const float* __restrict__ masks,
                            float*       __restrict__ out,
                            int C, int H, int W, int MH, int MW) {
    __shared__ __align__(16) float s_reg[CG * CH_DW];      // 43,648 B
    __shared__ ushort4 s_idx[NSAMP];                       //  1,568 B (byte offs)
    __shared__ float4  s_w[NSAMP];                         //  3,136 B

    const int cgp = blockIdx.x;          // channel group (fast dim: 32 blocks/roi co-run)
    const int r   = blockIdx.y;
    const int tid = threadIdx.x;

    const float* roi = rois + (size_t)r * 5;
    const int   b  = (int)roi[0];
    const float x1 = roi[1], y1 = roi[2], x2 = roi[3], y2 = roi[4];

    const float roi_start_w = x1 * SCALE;
    const float roi_start_h = y1 * SCALE;
    const float roi_w = fmaxf((x2 - x1 + 1.0f) * SCALE, 1.0f);
    const float roi_h = fmaxf((y2 - y1 + 1.0f) * SCALE, 1.0f);
    const float bin_w = roi_w * (1.0f / OUT_W);
    const float bin_h = roi_h * (1.0f / OUT_H);

    // region bounds (uniform per block); in-spec worst case 34 rows x 10
    // float4-cols from x_lo4; clamped defensively for out-of-spec rois.
    int y_lo = (int)floorf(roi_start_h); y_lo = max(0, min(y_lo, H - 1));
    int x_lo = (int)floorf(roi_start_w); x_lo = max(0, min(x_lo, W - 1));
    const int y_hi = max(y_lo, min((int)floorf(roi_start_h + roi_h) + 1, H - 1));
    const int x_hi = max(x_lo, min((int)floorf(roi_start_w + roi_w) + 1, W - 1));
    const int rows  = min(y_hi - y_lo + 1, RDIM);
    const int x_lo4 = x_lo & ~3;                     // 16B-aligned origin
    const int cols4 = min((x_hi - x_lo4 + 4) >> 2, RCOLS4);
    // x_lo4+4k (k<cols4) is a multiple of 4, <= x_hi <= W-1 -> <= W-4 when
    // W%4==0 (gated at launch): every 16 B read in-bounds and aligned.
    const int rs_dw = cols4 << 2;                    // region row stride (dwords)

    // ---- phase A: sample coords + issue mask loads (threads 0..195) ----
    float yy = 0.f, xx = 0.f, m00 = 0.f, m01 = 0.f, m10 = 0.f, m11 = 0.f;
    float mly = 0.f, mlx = 0.f;
    if (tid < NSAMP) {
        const int bin = tid >> 2;          // 0..48
        const int sub = tid & 3;           // 0..3
        const int ph  = bin / OUT_W, pw = bin % OUT_W;
        const int iy  = sub >> 1,   ix = sub & 1;
        yy = roi_start_h + ((float)ph + ((float)iy + 0.5f) * (1.0f / S)) * bin_h;
        xx = roi_start_w + ((float)pw + ((float)ix + 0.5f) * (1.0f / S)) * bin_w;

        const float* msk = masks + (size_t)r * MH * MW;
        float my = fminf(fmaxf(yy * (1.0f / SCALE) - y1, 0.0f), y2 - y1);
        float mx = fminf(fmaxf(xx * (1.0f / SCALE) - x1, 0.0f), x2 - x1);
        my = fminf(fmaxf(my, 0.0f), (float)(MH - 1));
        mx = fminf(fmaxf(mx, 0.0f), (float)(MW - 1));
        const int my0 = (int)floorf(my), mx0 = (int)floorf(mx);
        const int my1 = min(my0 + 1, MH - 1), mx1 = min(mx0 + 1, MW - 1);
        mly = my - (float)my0; mlx = mx - (float)mx0;
        m00 = msk[my0 * MW + mx0];                   // issued early; consumed in C
        m01 = msk[my0 * MW + mx1];
        m10 = msk[my1 * MW + mx0];
        m11 = msk[my1 * MW + mx1];
    }

    // ---- phase B: stage region f32 via global_load_lds (all threads) ----
    {
        const int wv   = tid >> 6;         // wave 0..3 -> channels 2wv, 2wv+1
        const int lane = tid & 63;
        const int items = rows * cols4;
        const int nch   = (items + 63) >> 6;
        const int imax  = max(items - 64, 0);
        const float rcp = 1.0f / (float)cols4;
        const size_t HWs = (size_t)H * W;
#pragma unroll
        for (int cc = 0; cc < 2; ++cc) {
            const int ch = 2 * wv + cc;
            const float* src0 = features
                + ((size_t)b * C + (size_t)(cgp * CG + ch)) * HWs
                + (size_t)y_lo * W + x_lo4;
            float* lbase = s_reg + ch * CH_DW;
            for (int j = 0; j < nch; ++j) {
                const int bi = min(j << 6, imax);          // overlapped tail chunk
                const int it = min(bi + lane, items - 1);  // clamped (dup slots unread)
                int ry = (int)((float)it * rcp);
                int k  = it - ry * cols4;
                if (k < 0)           { --ry; k += cols4; }
                else if (k >= cols4) { ++ry; k -= cols4; }
                const float* src = src0 + (ry * W + (k << 2));
                // HW scatters: LDS dest = uniform base + lane*16
                __builtin_amdgcn_global_load_lds(
                    (const __attribute__((address_space(1))) unsigned int*)src,
                    (__attribute__((address_space(3))) unsigned int*)(lbase + (bi << 2)),
                    16, 0, 0);
            }
        }
    }

    // ---- phase C: finish geometry (threads 0..195) ----
    if (tid < NSAMP) {
        const bool valid = (yy > -1.0f) && (yy < (float)H) && (xx > -1.0f) && (xx < (float)W);
        const float mhy = 1.0f - mly, mhx = 1.0f - mlx;
        const float wgt = mhy * mhx * m00 + mhy * mlx * m01
                        + mly * mhx * m10 + mly * mlx * m11;

        const float yc = fminf(fmaxf(yy, 0.0f), (float)(H - 1));
        const float xc = fminf(fmaxf(xx, 0.0f), (float)(W - 1));
        const int y0  = (int)floorf(yc), x0 = (int)floorf(xc);
        const int y1i = min(y0 + 1, H - 1), x1i = min(x0 + 1, W - 1);
        const float ly = yc - (float)y0, lx = xc - (float)x0;
        const float hy = 1.0f - ly,      hx = 1.0f - lx;

        const int ly0 = min(max(y0  - y_lo,  0), rows - 1);
        const int ly1 = min(max(y1i - y_lo,  0), rows - 1);
        const int lx0 = min(max(x0  - x_lo4, 0), rs_dw - 1);
        const int lx1 = min(max(x1i - x_lo4, 0), rs_dw - 1);

        const float scale_all = (valid ? wgt : 0.0f) * (1.0f / (float)(S * S));
        ushort4 o;                                    // byte offsets in channel region
        o.x = (ushort_t)((ly0 * rs_dw + lx0) << 2);
        o.y = (ushort_t)((ly0 * rs_dw + lx1) << 2);
        o.z = (ushort_t)((ly1 * rs_dw + lx0) << 2);
        o.w = (ushort_t)((ly1 * rs_dw + lx1) << 2);
        s_idx[tid] = o;
        float4 w4;
        w4.x = hy * hx * scale_all;
        w4.y = hy * lx * scale_all;
        w4.z = ly * hx * scale_all;
        w4.w = ly * lx * scale_all;
        s_w[tid] = w4;
    }
    __syncthreads();   // drains staging vmcnt + publishes s_idx/s_w

    // ---- phase D: gather: thread = (c, sg); bins sg and sg+32 ----
    const int c  = tid & 7;
    const int sg = tid >> 3;             // 0..31
    const char* creg = (const char*)(s_reg + c * CH_DW);

    float acc0 = 0.0f, acc1 = 0.0f;
#pragma unroll
    for (int sub = 0; sub < 4; ++sub) {
        const int s0 = (sg << 2) + sub;
        const ushort4 o = s_idx[s0];
        const float4  w = s_w[s0];
        acc0 = fmaf(w.x, *(const float*)(creg + o.x), acc0);
        acc0 = fmaf(w.y, *(const float*)(creg + o.y), acc0);
        acc0 = fmaf(w.z, *(const float*)(creg + o.z), acc0);
        acc0 = fmaf(w.w, *(const float*)(creg + o.w), acc0);
    }
    const int bin1 = sg + 32;
    if (bin1 < NBIN) {
#pragma unroll
        for (int sub = 0; sub < 4; ++sub) {
            const int s1 = (bin1 << 2) + sub;
            const ushort4 o = s_idx[s1];
            const float4  w = s_w[s1];
            acc1 = fmaf(w.x, *(const float*)(creg + o.x), acc1);
            acc1 = fmaf(w.y, *(const float*)(creg + o.y), acc1);
            acc1 = fmaf(w.z, *(const float*)(creg + o.z), acc1);
            acc1 = fmaf(w.w, *(const float*)(creg + o.w), acc1);
        }
    }
    __syncthreads();   // region reads done before LDS reuse

    // ---- phase E: stage results (reuse region LDS), coalesced write ----
    float* s_out = (float*)s_reg;               // 8*49 f32 = 1.57 KB
    s_out[c * NBIN + sg] = acc0;
    if (bin1 < NBIN) s_out[c * NBIN + bin1] = acc1;
    __syncthreads();

    float* outr = out + ((size_t)r * C + (size_t)cgp * CG) * NBIN;
    for (int i = tid; i < CG * NBIN; i += 256)
        outr[i] = s_out[i];
}

// ---------------------------------------------------------------------------
// Fallback for unexpected shapes. No workspace either.
// ---------------------------------------------------------------------------
__global__ __launch_bounds__(256)
void mask_roialign_kernel(const float* __restrict__ features,
                          const float* __restrict__ rois,
                          const float* __restrict__ masks,
                          float*       __restrict__ out,
                          int C, int H, int W, int MH, int MW) {
    int blk = blockIdx.x;
    int pw  = blk % OUT_W;
    int ph  = (blk / OUT_W) % OUT_H;
    int r   = blk / (OUT_W * OUT_H);
    int c   = threadIdx.x;
    if (c >= C) return;

    const float* roi = rois + (size_t)r * 5;
    int   b  = (int)roi[0];
    float x1 = roi[1], y1 = roi[2], x2 = roi[3], y2 = roi[4];

    float roi_start_w = x1 * SCALE;
    float roi_start_h = y1 * SCALE;
    float roi_w = fmaxf((x2 - x1 + 1.0f) * SCALE, 1.0f);
    float roi_h = fmaxf((y2 - y1 + 1.0f) * SCALE, 1.0f);
    float bin_w = roi_w / (float)OUT_W;
    float bin_h = roi_h / (float)OUT_H;

    const float* fch = features + ((size_t)b * C + c) * (size_t)(H * W);
    const float* msk = masks + (size_t)r * MH * MW;

    float acc = 0.0f;
#pragma unroll
    for (int iy = 0; iy < S; ++iy) {
        float yy = roi_start_h + ((float)ph + ((float)iy + 0.5f) / (float)S) * bin_h;
#pragma unroll
        for (int ix = 0; ix < S; ++ix) {
            float xx = roi_start_w + ((float)pw + ((float)ix + 0.5f) / (float)S) * bin_w;
            bool valid = (yy > -1.0f) && (yy < (float)H) && (xx > -1.0f) && (xx < (float)W);
            float my = fminf(fmaxf(yy / SCALE - y1, 0.0f), fminf(y2 - y1, (float)(MH - 1)));
            float mx = fminf(fmaxf(xx / SCALE - x1, 0.0f), fminf(x2 - x1, (float)(MW - 1)));
            int my0 = (int)floorf(my), mx0 = (int)floorf(mx);
            int my1 = min(my0 + 1, MH - 1), mx1 = min(mx0 + 1, MW - 1);
            float mly = my - my0, mlx = mx - mx0, mhy = 1.0f - mly, mhx = 1.0f - mlx;
            float wgt = mhy * mhx * msk[my0 * MW + mx0] + mhy * mlx * msk[my0 * MW + mx1]
                      + mly * mhx * msk[my1 * MW + mx0] + mly * mlx * msk[my1 * MW + mx1];
            if (valid) {
                float yc = fminf(fmaxf(yy, 0.0f), (float)(H - 1));
                float xc = fminf(fmaxf(xx, 0.0f), (float)(W - 1));
                int y0 = (int)floorf(yc), x0 = (int)floorf(xc);
                int y1i = min(y0 + 1, H - 1), x1i = min(x0 + 1, W - 1);
                float ly = yc - y0, lx = xc - x0, hy = 1.0f - ly, hx = 1.0f - lx;
                float v = hy * hx * fch[y0  * W + x0 ] + hy * lx * fch[y0  * W + x1i]
                        + ly * hx * fch[y1i * W + x0 ] + ly * lx * fch[y1i * W + x1i];
                acc += wgt * v;
            }
        }
    }
    out[((size_t)r * C + c) * (size_t)NBIN + ph * OUT_W + pw] = acc * (1.0f / (S * S));
}

extern "C" void kernel_launch(void* const* d_in, const int* in_sizes, int n_in,
                              void* d_out, int out_size, void* d_ws, size_t ws_size,
                              hipStream_t stream) {
    const float* features = (const float*)d_in[0];
    const float* rois     = (const float*)d_in[1];
    const float* masks    = (const float*)d_in[2];
    float*       out      = (float*)d_out;

    const int R  = in_sizes[1] / 5;                       // 512
    const int C  = out_size / (R * NBIN);                 // 256
    const int H  = 200, W = 200;                          // fixed by reference
    const int MH = 128, MW = 128;                         // fixed by reference

    (void)d_ws; (void)ws_size;                            // workspace-free on purpose

    if ((C % CG == 0) && (W % 4 == 0)) {
        roialign_direct_kernel<<<dim3(C / CG, R), dim3(256), 0, stream>>>(
            features, rois, masks, out, C, H, W, MH, MW);
    } else {
        mask_roialign_kernel<<<dim3(R * NBIN), dim3(256), 0, stream>>>(
            features, rois, masks, out, C, H, W, MH, MW);
    }
}

// Round 7
// 180.719 us; speedup vs baseline: 1.0920x; 1.0920x over previous
//
#include <hip/hip_runtime.h>
#include <hip/hip_bf16.h>

// ShapeAwareRoIAlign: mask-weighted RoIAlign.
//   features: [N=2, C=256, H=200, W=200] f32 (NCHW, 164 MB)
//   rois:     [R=512, 5] f32  (b, x1, y1, x2, y2) inclusive image coords
//   masks:    [R, MH=128, MW=128] f32
//   out:      [R, C, 7, 7] f32
//
// Round 13 (= round 12 with the bit_cast compile fix: __hip_bfloat162 is not
// trivially copyable -> use __builtin_memcpy, which lowers to a reg move).
// Harness model (residual accounting r0-r5): ~110 us/iter of fillBuffer
// restore + launch overhead is UNCONDITIONAL. Total = ~110 + kernel.
// Kernel byte floor ~30 us (168 MB fetch + 25.7 MB write at 6.6 TB/s).
// r4 (bf16-pack staging, 6 blocks/CU) = 68.7 us, VALU-issue-bound: manual
// f2bf x8 + or x4 ~ 44 VALU per 32 B staged ~ 50 us GPU-wide.
// r5 (global_load_lds f32) = 85 us: f32 doubled LDS -> 3 blocks/CU ->
// latency no longer hidden. r4 structure + v_cvt_pk_bf16_f32 staging
// (via __float22bfloat162_rn: 4 VALU per item instead of ~36) + early
// mask-load issue.

constexpr int   OUT_H = 7, OUT_W = 7;
constexpr int   NBIN  = OUT_H * OUT_W;     // 49
constexpr float SCALE = 0.25f;
constexpr int   S     = 2;
constexpr int   NSAMP = NBIN * S * S;      // 196 sample points per roi
constexpr int   CG    = 8;                 // channels per block
constexpr int   NPAIR = CG / 2;            // 4 channel pairs
constexpr int   RDIM  = 34;                // max region rows
constexpr int   RCOLS = 40;                // padded region cols (10 float4)
constexpr int   PSTRIDE = RDIM * RCOLS * 2 + 4;  // u16 units per pair region (2724):
                                           // 8B-aligned; 1362 dwords mod 32 = 18
                                           // -> pair bases on distinct banks

typedef unsigned short ushort_t;

__device__ __forceinline__ unsigned pack_bf16_pair(float e, float o) {
    // low 16 = even channel, high 16 = odd channel; RNE via v_cvt_pk_bf16_f32
    __hip_bfloat162 h2 = __float22bfloat162_rn(make_float2(e, o));
    unsigned u;
    __builtin_memcpy(&u, &h2, sizeof(u));
    return u;
}

// ---------------------------------------------------------------------------
// Fused direct kernel: grid (C/8, R), 256 threads, no workspace.
//   A: threads 0..195 compute sample coords and ISSUE 4 mask loads.
//   B: stage region [pair][px][2ch] bf16. 8 groups of 32 lanes =
//      (pair, half); lane loads float4 from even AND odd channel of its
//      pair (2 VMEM in flight), cvt_pk-packs, 2x b64 LDS writes.
//   C: threads 0..195 finish geometry: region-local BYTE offsets + folded
//      weights (bilinear*mask*valid*0.25) -> s_idx/s_w.
//   D: gather: thread = (pair, bin) (196 active); per corner one
//      ds_read_b32 = 2 channels; 1 shl + 1 and + 2 fmac.
//   E: results via LDS (reuse region buffer), coalesced out.
// ---------------------------------------------------------------------------
__global__ __launch_bounds__(256, 6)
void roialign_direct_kernel(const float* __restrict__ features,
                            const float* __restrict__ rois,
                            const float* __restrict__ masks,
                            float*       __restrict__ out,
                            int C, int H, int W, int MH, int MW) {
    __shared__ __align__(16) ushort_t s_reg[NPAIR * PSTRIDE];  // 21,792 B
    __shared__ ushort4 s_idx[NSAMP];                           //  1,568 B (byte offs)
    __shared__ float4  s_w[NSAMP];                             //  3,136 B

    const int cgp = blockIdx.x;          // channel group (fast dim: 32 blocks/roi co-run)
    const int r   = blockIdx.y;
    const int tid = threadIdx.x;

    const float* roi = rois + (size_t)r * 5;
    const int   b  = (int)roi[0];
    const float x1 = roi[1], y1 = roi[2], x2 = roi[3], y2 = roi[4];

    const float roi_start_w = x1 * SCALE;
    const float roi_start_h = y1 * SCALE;
    const float roi_w = fmaxf((x2 - x1 + 1.0f) * SCALE, 1.0f);
    const float roi_h = fmaxf((y2 - y1 + 1.0f) * SCALE, 1.0f);
    const float bin_w = roi_w * (1.0f / OUT_W);
    const float bin_h = roi_h * (1.0f / OUT_H);

    // region bounds (uniform per block); in-spec worst case 34 rows x 10
    // float4-cols from x_lo4; clamped defensively for out-of-spec rois.
    int y_lo = (int)floorf(roi_start_h); y_lo = max(0, min(y_lo, H - 1));
    int x_lo = (int)floorf(roi_start_w); x_lo = max(0, min(x_lo, W - 1));
    const int y_hi = max(y_lo, min((int)floorf(roi_start_h + roi_h) + 1, H - 1));
    const int x_hi = max(x_lo, min((int)floorf(roi_start_w + roi_w) + 1, W - 1));
    const int rows  = min(y_hi - y_lo + 1, RDIM);
    const int x_lo4 = x_lo & ~3;                    // 16B-aligned origin
    const int cols4 = min((x_hi - x_lo4 + 4) >> 2, RCOLS / 4);
    // x_lo4+4k (k<cols4) is a multiple of 4, <= x_hi <= W-1 -> <= W-4 when
    // W%4==0 (gated at launch): every float4 read in-bounds and 16B-aligned.

    // ---- phase A: sample coords + issue mask loads (threads 0..195) ----
    float yy = 0.f, xx = 0.f, m00 = 0.f, m01 = 0.f, m10 = 0.f, m11 = 0.f;
    float mly = 0.f, mlx = 0.f;
    if (tid < NSAMP) {
        const int bin = tid >> 2;          // 0..48
        const int sub = tid & 3;           // 0..3
        const int ph  = bin / OUT_W, pw = bin % OUT_W;
        const int iy  = sub >> 1,   ix = sub & 1;
        yy = roi_start_h + ((float)ph + ((float)iy + 0.5f) * (1.0f / S)) * bin_h;
        xx = roi_start_w + ((float)pw + ((float)ix + 0.5f) * (1.0f / S)) * bin_w;

        const float* msk = masks + (size_t)r * MH * MW;
        float my = fminf(fmaxf(yy * (1.0f / SCALE) - y1, 0.0f), y2 - y1);
        float mx = fminf(fmaxf(xx * (1.0f / SCALE) - x1, 0.0f), x2 - x1);
        my = fminf(fmaxf(my, 0.0f), (float)(MH - 1));
        mx = fminf(fmaxf(mx, 0.0f), (float)(MW - 1));
        const int my0 = (int)floorf(my), mx0 = (int)floorf(mx);
        const int my1 = min(my0 + 1, MH - 1), mx1 = min(mx0 + 1, MW - 1);
        mly = my - (float)my0; mlx = mx - (float)mx0;
        m00 = msk[my0 * MW + mx0];                   // issued early; consumed in C
        m01 = msk[my0 * MW + mx1];
        m10 = msk[my1 * MW + mx0];
        m11 = msk[my1 * MW + mx1];
    }

    // ---- phase B: stage feature region (packed channel pairs) ----
    {
        const int g    = tid >> 5;        // 0..7
        const int lane = tid & 31;
        const int pr   = g >> 1;          // pair 0..3
        const int part = g & 1;           // phase half
        const size_t HWs = (size_t)H * W;
        const float* srcE = features + ((size_t)b * C + (size_t)(cgp * CG + 2 * pr)) * HWs
                          + (size_t)y_lo * W + x_lo4;
        const float* srcO = srcE + HWs;
        unsigned* dp32base = (unsigned*)(s_reg + pr * PSTRIDE);
        const int items = rows * cols4;
        const float rcp = 1.0f / (float)cols4;
#pragma unroll 2
        for (int it = lane + part * 32; it < items; it += 64) {
            int ry = (int)((float)it * rcp);
            int k  = it - ry * cols4;
            if (k >= cols4) { ry++; k -= cols4; }
            if (k < 0)      { ry--; k += cols4; }
            const float4 vE = *(const float4*)(srcE + ry * W + 4 * k);
            const float4 vO = *(const float4*)(srcO + ry * W + 4 * k);
            const int pix = ry * RCOLS + 4 * k;              // dword index
            uint2 a, c2;
            a.x  = pack_bf16_pair(vE.x, vO.x);
            a.y  = pack_bf16_pair(vE.y, vO.y);
            c2.x = pack_bf16_pair(vE.z, vO.z);
            c2.y = pack_bf16_pair(vE.w, vO.w);
            *(uint2*)(dp32base + pix)     = a;               // 8B, 8B-aligned
            *(uint2*)(dp32base + pix + 2) = c2;
        }
    }

    // ---- phase C: finish geometry (threads 0..195) ----
    if (tid < NSAMP) {
        const bool valid = (yy > -1.0f) && (yy < (float)H) && (xx > -1.0f) && (xx < (float)W);
        const float mhy = 1.0f - mly, mhx = 1.0f - mlx;
        const float wgt = mhy * mhx * m00 + mhy * mlx * m01
                        + mly * mhx * m10 + mly * mlx * m11;

        const float yc = fminf(fmaxf(yy, 0.0f), (float)(H - 1));
        const float xc = fminf(fmaxf(xx, 0.0f), (float)(W - 1));
        const int y0  = (int)floorf(yc), x0 = (int)floorf(xc);
        const int y1i = min(y0 + 1, H - 1), x1i = min(x0 + 1, W - 1);
        const float ly = yc - (float)y0, lx = xc - (float)x0;
        const float hy = 1.0f - ly,      hx = 1.0f - lx;

        const int ly0 = min(max(y0  - y_lo,  0), RDIM  - 1);
        const int ly1 = min(max(y1i - y_lo,  0), RDIM  - 1);
        const int lx0 = min(max(x0  - x_lo4, 0), RCOLS - 1);
        const int lx1 = min(max(x1i - x_lo4, 0), RCOLS - 1);

        const float scale_all = (valid ? wgt : 0.0f) * (1.0f / (float)(S * S));
        ushort4 o;                                    // byte offsets = dword_pix*4
        o.x = (ushort_t)((ly0 * RCOLS + lx0) * 4);
        o.y = (ushort_t)((ly0 * RCOLS + lx1) * 4);
        o.z = (ushort_t)((ly1 * RCOLS + lx0) * 4);
        o.w = (ushort_t)((ly1 * RCOLS + lx1) * 4);
        s_idx[tid] = o;
        float4 w4;
        w4.x = hy * hx * scale_all;
        w4.y = hy * lx * scale_all;
        w4.z = ly * hx * scale_all;
        w4.w = ly * lx * scale_all;
        s_w[tid] = w4;
    }
    __syncthreads();

    // ---- phase D: gather: thread = (pair, bin); 2 channels per thread ----
    float accE = 0.0f, accO = 0.0f;
    const int pr  = tid & 3;
    const int bin = tid >> 2;
    if (tid < NSAMP) {                                 // 196 = 4 pairs x 49 bins
        const char* base = (const char*)s_reg + pr * (PSTRIDE * 2);
#pragma unroll
        for (int sub = 0; sub < 4; ++sub) {
            const int s = bin * 4 + sub;
            const ushort4 off = s_idx[s];              // broadcast across 4 pr lanes
            const float4  w   = s_w[s];
            const unsigned q0 = *(const unsigned*)(base + off.x);
            const unsigned q1 = *(const unsigned*)(base + off.y);
            const unsigned q2 = *(const unsigned*)(base + off.z);
            const unsigned q3 = *(const unsigned*)(base + off.w);
            accE = fmaf(w.x, __uint_as_float(q0 << 16),          accE);
            accO = fmaf(w.x, __uint_as_float(q0 & 0xffff0000u),  accO);
            accE = fmaf(w.y, __uint_as_float(q1 << 16),          accE);
            accO = fmaf(w.y, __uint_as_float(q1 & 0xffff0000u),  accO);
            accE = fmaf(w.z, __uint_as_float(q2 << 16),          accE);
            accO = fmaf(w.z, __uint_as_float(q2 & 0xffff0000u),  accO);
            accE = fmaf(w.w, __uint_as_float(q3 << 16),          accE);
            accO = fmaf(w.w, __uint_as_float(q3 & 0xffff0000u),  accO);
        }
    }
    __syncthreads();   // region reads done before LDS reuse

    // ---- phase E: stage results (reuse region LDS), coalesced write ----
    float* s_out = (float*)s_reg;               // 8*49 f32 = 1.57 KB
    if (tid < NSAMP) {
        s_out[(2 * pr + 0) * NBIN + bin] = accE;
        s_out[(2 * pr + 1) * NBIN + bin] = accO;
    }
    __syncthreads();

    float* outr = out + ((size_t)r * C + (size_t)cgp * CG) * NBIN;
    for (int i = tid; i < CG * NBIN; i += 256)
        outr[i] = s_out[i];
}

// ---------------------------------------------------------------------------
// Fallback for unexpected shapes. No workspace either.
// ---------------------------------------------------------------------------
__global__ __launch_bounds__(256)
void mask_roialign_kernel(const float* __restrict__ features,
                          const float* __restrict__ rois,
                          const float* __restrict__ masks,
                          float*       __restrict__ out,
                          int C, int H, int W, int MH, int MW) {
    int blk = blockIdx.x;
    int pw  = blk % OUT_W;
    int ph  = (blk / OUT_W) % OUT_H;
    int r   = blk / (OUT_W * OUT_H);
    int c   = threadIdx.x;
    if (c >= C) return;

    const float* roi = rois + (size_t)r * 5;
    int   b  = (int)roi[0];
    float x1 = roi[1], y1 = roi[2], x2 = roi[3], y2 = roi[4];

    float roi_start_w = x1 * SCALE;
    float roi_start_h = y1 * SCALE;
    float roi_w = fmaxf((x2 - x1 + 1.0f) * SCALE, 1.0f);
    float roi_h = fmaxf((y2 - y1 + 1.0f) * SCALE, 1.0f);
    float bin_w = roi_w / (float)OUT_W;
    float bin_h = roi_h / (float)OUT_H;

    const float* fch = features + ((size_t)b * C + c) * (size_t)(H * W);
    const float* msk = masks + (size_t)r * MH * MW;

    float acc = 0.0f;
#pragma unroll
    for (int iy = 0; iy < S; ++iy) {
        float yy = roi_start_h + ((float)ph + ((float)iy + 0.5f) / (float)S) * bin_h;
#pragma unroll
        for (int ix = 0; ix < S; ++ix) {
            float xx = roi_start_w + ((float)pw + ((float)ix + 0.5f) / (float)S) * bin_w;
            bool valid = (yy > -1.0f) && (yy < (float)H) && (xx > -1.0f) && (xx < (float)W);
            float my = fminf(fmaxf(yy / SCALE - y1, 0.0f), fminf(y2 - y1, (float)(MH - 1)));
            float mx = fminf(fmaxf(xx / SCALE - x1, 0.0f), fminf(x2 - x1, (float)(MW - 1)));
            int my0 = (int)floorf(my), mx0 = (int)floorf(mx);
            int my1 = min(my0 + 1, MH - 1), mx1 = min(mx0 + 1, MW - 1);
            float mly = my - my0, mlx = mx - mx0, mhy = 1.0f - mly, mhx = 1.0f - mlx;
            float wgt = mhy * mhx * msk[my0 * MW + mx0] + mhy * mlx * msk[my0 * MW + mx1]
                      + mly * mhx * msk[my1 * MW + mx0] + mly * mlx * msk[my1 * MW + mx1];
            if (valid) {
                float yc = fminf(fmaxf(yy, 0.0f), (float)(H - 1));
                float xc = fminf(fmaxf(xx, 0.0f), (float)(W - 1));
                int y0 = (int)floorf(yc), x0 = (int)floorf(xc);
                int y1i = min(y0 + 1, H - 1), x1i = min(x0 + 1, W - 1);
                float ly = yc - y0, lx = xc - x0, hy = 1.0f - ly, hx = 1.0f - lx;
                float v = hy * hx * fch[y0  * W + x0 ] + hy * lx * fch[y0  * W + x1i]
                        + ly * hx * fch[y1i * W + x0 ] + ly * lx * fch[y1i * W + x1i];
                acc += wgt * v;
            }
        }
    }
    out[((size_t)r * C + c) * (size_t)NBIN + ph * OUT_W + pw] = acc * (1.0f / (S * S));
}

extern "C" void kernel_launch(void* const* d_in, const int* in_sizes, int n_in,
                              void* d_out, int out_size, void* d_ws, size_t ws_size,
                              hipStream_t stream) {
    const float* features = (const float*)d_in[0];
    const float* rois     = (const float*)d_in[1];
    const float* masks    = (const float*)d_in[2];
    float*       out      = (float*)d_out;

    const int R  = in_sizes[1] / 5;                       // 512
    const int C  = out_size / (R * NBIN);                 // 256
    const int H  = 200, W = 200;                          // fixed by reference
    const int MH = 128, MW = 128;                         // fixed by reference

    (void)d_ws; (void)ws_size;                            // workspace-free on purpose

    if ((C % CG == 0) && (W % 4 == 0)) {
        roialign_direct_kernel<<<dim3(C / CG, R), dim3(256), 0, stream>>>(
            features, rois, masks, out, C, H, W, MH, MW);
    } else {
        mask_roialign_kernel<<<dim3(R * NBIN), dim3(256), 0, stream>>>(
            features, rois, masks, out, C, H, W, MH, MW);
    }
}